// Round 4
// baseline (339.545 us; speedup 1.0000x reference)
//
#include <hip/hip_runtime.h>
#include <stdint.h>

// Problem constants
#define BB      131072
#define D_IN    100
#define HN      50
#define TT      100
#define DT_C    0.01f
#define GAMMA_C 0.05f
#define I0_C    0.12f

// Packed-weight layout in d_ws (floats) — identical footprint to round 3 (fits ws_size):
#define PW_W0T 0      // W0T [100][50], W0T[i][j] = W0[j][i]
#define PW_B0  5000   // b0 [50]
#define PW_W1  5050   // W1 [50][50] row-major
#define PW_B1  7550   // b1 [50]
#define PW_W2  7600   // W2 [99][50] row-major
#define PW_B2  12550  // b2 [99]   (total 12649 floats = 50,596 B)

// 4-byte-aligned float4: gfx9 global_load_dwordx4 only needs dword alignment.
typedef float f4u __attribute__((ext_vector_type(4), aligned(4)));

__global__ void pack_kernel(const float* __restrict__ W0, const float* __restrict__ b0,
                            const float* __restrict__ W1, const float* __restrict__ b1,
                            const float* __restrict__ W2, const float* __restrict__ b2,
                            float* __restrict__ ws)
{
    const int gid = blockIdx.x * blockDim.x + threadIdx.x;
    const int gsz = gridDim.x * blockDim.x;
    for (int idx = gid; idx < 5000; idx += gsz) {           // transpose W0 [50][100] -> [100][50]
        int i = idx / 50, j = idx % 50;
        ws[PW_W0T + idx] = W0[j * 100 + i];
    }
    for (int idx = gid; idx < 50; idx += gsz)   ws[PW_B0 + idx] = b0[idx];
    for (int idx = gid; idx < 2500; idx += gsz) ws[PW_W1 + idx] = W1[idx];
    for (int idx = gid; idx < 50; idx += gsz)   ws[PW_B1 + idx] = b1[idx];
    for (int idx = gid; idx < 4950; idx += gsz) ws[PW_W2 + idx] = W2[idx];
    for (int idx = gid; idx < 99; idx += gsz)   ws[PW_B2 + idx] = b2[idx];
}

// Launder a pointer through VGPRs so the compiler cannot prove uniformity ->
// weight loads become VMEM global_load (deep pipelining), not s_load chains.
__device__ __forceinline__ const float* vptr(const float* p) {
    uint64_t u = (uint64_t)p;
    uint32_t lo = (uint32_t)u, hi = (uint32_t)(u >> 32);
    asm("v_mov_b32 %0, %1" : "=v"(lo) : "v"(lo));
    asm("v_mov_b32 %0, %1" : "=v"(hi) : "v"(hi));
    return (const float*)(((uint64_t)hi << 32) | (uint64_t)lo);
}

// 50-elem dot, weights via unaligned-ok float4 vector loads, h statically indexed.
__device__ __forceinline__ float dot50v(const float* __restrict__ wr, const float h[HN]) {
    float s0 = 0.f, s1 = 0.f, s2 = 0.f, s3 = 0.f;
    #pragma unroll
    for (int q = 0; q < 12; ++q) {
        f4u wq = *(const f4u*)(wr + 4 * q);
        s0 = fmaf(h[4 * q + 0], wq.x, s0);
        s1 = fmaf(h[4 * q + 1], wq.y, s1);
        s2 = fmaf(h[4 * q + 2], wq.z, s2);
        s3 = fmaf(h[4 * q + 3], wq.w, s3);
    }
    s0 = fmaf(h[48], wr[48], s0);
    s1 = fmaf(h[49], wr[49], s1);
    return (s0 + s2) + (s1 + s3);
}

#define BLK    128
#define STRIDE 101   // odd -> LDS bank-conflict-free per-thread rows

__global__ __launch_bounds__(BLK, 3) void net_kernel(
    const float* __restrict__ x,
    const float* __restrict__ w_,    // packed weights in d_ws
    float* __restrict__ out)
{
    __shared__ float lbuf[BLK * STRIDE];   // 51,712 B -> 3 blocks/CU
    const int tid = threadIdx.x;
    const int b = blockIdx.x * BLK + tid;
    const float* wv = vptr(w_);
    float* hrow = lbuf + tid * STRIDE;     // this thread's private LDS row

    // ---- Layer 0: acc = b0 + x . W0T, streaming 5000 weights sequentially ----
    float acc[HN];
    {
        #pragma unroll
        for (int q = 0; q < 12; ++q) {
            f4u v = *(const f4u*)(wv + PW_B0 + 4 * q);
            acc[4 * q + 0] = v.x; acc[4 * q + 1] = v.y;
            acc[4 * q + 2] = v.z; acc[4 * q + 3] = v.w;
        }
        acc[48] = wv[PW_B0 + 48];
        acc[49] = wv[PW_B0 + 49];
    }
    const f4u* xr = (const f4u*)(x + (size_t)b * D_IN);
    #pragma unroll 1
    for (int i4 = 0; i4 < 25; ++i4) {
        f4u xv = xr[i4];
        const float xs[4] = { xv.x, xv.y, xv.z, xv.w };
        const float* wbase = wv + PW_W0T + i4 * 200;   // 4 W0T rows = 200 floats, 16B-aligned
        #pragma unroll
        for (int f = 0; f < 50; ++f) {
            f4u wq = *(const f4u*)(wbase + 4 * f);
            #pragma unroll
            for (int t = 0; t < 4; ++t) {
                const int e = 4 * f + t;       // 0..199
                const int r = e / 50;          // which x element (static)
                const int j = e % 50;          // which neuron (static)
                const float wt = (t == 0) ? wq.x : (t == 1) ? wq.y : (t == 2) ? wq.z : wq.w;
                acc[j] = fmaf(xs[r], wt, acc[j]);
            }
        }
    }

    float h0[HN];
    #pragma unroll
    for (int j = 0; j < HN; ++j) h0[j] = fmaxf(acc[j], 0.0f);

    // ---- Layer 1 (rolled, results via private LDS row to keep code small) ----
    #pragma unroll 2
    for (int j = 0; j < HN; ++j) {
        float o = dot50v(wv + PW_W1 + 50 * j, h0) + wv[PW_B1 + j];
        hrow[j] = fmaxf(o, 0.0f);
    }
    float h1[HN];
    #pragma unroll
    for (int j = 0; j < HN; ++j) h1[j] = hrow[j];   // static-offset readback

    // ---- Layer 2 (rolled): raw dots o_k -> LDS row ----
    #pragma unroll 2
    for (int k = 0; k < 99; ++k) {
        hrow[k] = dot50v(wv + PW_W2 + 50 * k, h1) + wv[PW_B2 + k];
    }

    // ---- Euler scan, fully unrolled with static register outputs ----
    float I[TT];
    I[0] = I0_C;
    #pragma unroll
    for (int k = 1; k < TT; ++k) {
        float o = hrow[k - 1];                 // ds_read_b32, static offset, prefetchable
        float p = I[k - 1];
        I[k] = p + DT_C * (o * p * (1.0f - p) - GAMMA_C * p);
    }

    // ---- Burst store: 25 dwordx4 back-to-back -> L2 write-combines full lines ----
    f4u* orow = (f4u*)(out + (size_t)b * TT);  // 400 B rows, 16 B aligned
    #pragma unroll
    for (int q = 0; q < 25; ++q) {
        f4u v;
        v.x = I[4 * q + 0]; v.y = I[4 * q + 1];
        v.z = I[4 * q + 2]; v.w = I[4 * q + 3];
        orow[q] = v;
    }
}

extern "C" void kernel_launch(void* const* d_in, const int* in_sizes, int n_in,
                              void* d_out, int out_size, void* d_ws, size_t ws_size,
                              hipStream_t stream) {
    const float* x  = (const float*)d_in[0];
    const float* W0 = (const float*)d_in[1];
    const float* b0 = (const float*)d_in[2];
    const float* W1 = (const float*)d_in[3];
    const float* b1 = (const float*)d_in[4];
    const float* W2 = (const float*)d_in[5];
    const float* b2 = (const float*)d_in[6];
    float* out = (float*)d_out;
    float* ws  = (float*)d_ws;

    pack_kernel<<<dim3(64), dim3(256), 0, stream>>>(W0, b0, W1, b1, W2, b2, ws);
    net_kernel<<<dim3(BB / BLK), dim3(BLK), 0, stream>>>(x, ws, out);
}

// Round 5
// 124.277 us; speedup vs baseline: 2.7322x; 2.7322x over previous
//
#include <hip/hip_runtime.h>
#include <stdint.h>

// Problem constants
#define BB      131072
#define TT      100
#define DT_C    0.01f
#define GAMMA_C 0.05f
#define I0_C    0.12f

typedef short bf16x8 __attribute__((ext_vector_type(8)));
typedef float f32x4  __attribute__((ext_vector_type(4)));

// ws layout: B-fragments (bf16 as u16), then f32 biases (padded).
// Fragment = 1024 B = 64 lanes x 16 B; lane L holds B[k=kc*32+(L>>4)*8+j][n=nt*16+(L&15)], j=0..7.
#define F0_U16  0           // L0: 16 frags (kc 0..3, nt 0..3), K=100->128, N=50->64
#define F1_U16  (16*512)    // L1: 8 frags  (kc 0..1, nt 0..3), K=50->64,  N=50->64
#define F2_U16  (24*512)    // L2: 14 frags (kc 0..1, nt 0..6), K=50->64,  N=99->112
#define NFRAG_U16 (38*512)  // 19456 u16 = 38,912 B
#define B0_F    9728        // f32 index from ws base: 64 floats (b0 padded)
#define B1_F    (9728+64)   // 64 floats
#define B2_F    (9728+128)  // 112 floats

__device__ __host__ __forceinline__ uint16_t f2bf(float x) {
    uint32_t u = __builtin_bit_cast(uint32_t, x);
    return (uint16_t)((u + 0x7fffu + ((u >> 16) & 1u)) >> 16);   // RTNE
}

__global__ void pack_kernel(const float* __restrict__ W0, const float* __restrict__ b0,
                            const float* __restrict__ W1, const float* __restrict__ b1,
                            const float* __restrict__ W2, const float* __restrict__ b2,
                            uint16_t* __restrict__ wsu)
{
    const int gid = blockIdx.x * blockDim.x + threadIdx.x;
    const int gsz = gridDim.x * blockDim.x;
    float* wsf = (float*)wsu;

    for (int idx = gid; idx < NFRAG_U16; idx += gsz) {
        int f = idx >> 9;            // fragment id
        int r = idx & 511;
        int L = r >> 3, j = r & 7;
        int k8 = ((L >> 4) << 3) + j;    // 0..31 within K-chunk
        int n16 = L & 15;
        float v = 0.0f;
        if (f < 16) {                    // W0: B[k][n] = W0[n][k], k<100, n<50
            int kc = f >> 2, nt = f & 3;
            int kk = kc * 32 + k8, nn = nt * 16 + n16;
            if (kk < 100 && nn < 50) v = W0[nn * 100 + kk];
        } else if (f < 24) {             // W1: B[k][n] = W1[n][k], k<50, n<50
            int g = f - 16; int kc = g >> 2, nt = g & 3;
            int kk = kc * 32 + k8, nn = nt * 16 + n16;
            if (kk < 50 && nn < 50) v = W1[nn * 50 + kk];
        } else {                         // W2: B[k][n] = W2[n][k], k<50, n<99
            int g = f - 24; int kc = g / 7, nt = g % 7;
            int kk = kc * 32 + k8, nn = nt * 16 + n16;
            if (kk < 50 && nn < 99) v = W2[nn * 50 + kk];
        }
        wsu[idx] = f2bf(v);
    }
    for (int idx = gid; idx < 64; idx += gsz)  wsf[B0_F + idx] = (idx < 50) ? b0[idx] : 0.0f;
    for (int idx = gid; idx < 64; idx += gsz)  wsf[B1_F + idx] = (idx < 50) ? b1[idx] : 0.0f;
    for (int idx = gid; idx < 112; idx += gsz) wsf[B2_F + idx] = (idx < 99) ? b2[idx] : 0.0f;
}

// Per-wave LDS slab: 1856 floats (7424 B).
//   h0: u16 [16 m][88 n-stride]   at +0      (2816 B)   176 B rows -> 16B-aligned b128 reads
//   h1: u16 [16 m][88 n-stride]   at +1408 u16 (2816 B)
//   O:  f32 [16 m][116 t-stride]  at +0      (7424 B)   overlays h0/h1 after they die
#define SLAB_F 1856

__global__ __launch_bounds__(256, 2) void net_kernel(
    const float* __restrict__ x,
    const void*  __restrict__ wsv,
    float* __restrict__ out)
{
    __shared__ float lds[4 * SLAB_F];
    const int tid  = threadIdx.x;
    const int wave = tid >> 6, lane = tid & 63;
    const int quad = lane >> 4, l15 = lane & 15;
    float* slabF = lds + wave * SLAB_F;
    uint16_t* h0u = (uint16_t*)slabF;
    uint16_t* h1u = (uint16_t*)slabF + 1408;
    const uint16_t* wsu = (const uint16_t*)wsv;
    const float*    wsf = (const float*)wsv;

    const int row0 = (blockIdx.x * 4 + wave) * 16;   // this wave's 16 batch rows

    // ================= Layer 0: C0[16,64] = x[16,128p] * B0[128p,64] =================
    // A-fragments from x (f32 -> bf16), lane holds A[m=l15][k=kc*32+quad*8+j]
    bf16x8 a0[4];
    {
        const float* xrow = x + (size_t)(row0 + l15) * 100;
        #pragma unroll
        for (int kc = 0; kc < 3; ++kc) {
            const float4 p = *(const float4*)(xrow + kc * 32 + quad * 8);
            const float4 q = *(const float4*)(xrow + kc * 32 + quad * 8 + 4);
            bf16x8 f;
            f[0] = (short)f2bf(p.x); f[1] = (short)f2bf(p.y);
            f[2] = (short)f2bf(p.z); f[3] = (short)f2bf(p.w);
            f[4] = (short)f2bf(q.x); f[5] = (short)f2bf(q.y);
            f[6] = (short)f2bf(q.z); f[7] = (short)f2bf(q.w);
            a0[kc] = f;
        }
        bf16x8 f = {0, 0, 0, 0, 0, 0, 0, 0};
        if (quad == 0) {                       // k = 96..99 valid only
            const float4 p = *(const float4*)(xrow + 96);
            f[0] = (short)f2bf(p.x); f[1] = (short)f2bf(p.y);
            f[2] = (short)f2bf(p.z); f[3] = (short)f2bf(p.w);
        }
        a0[3] = f;
    }

    f32x4 acc0[4];
    #pragma unroll
    for (int nt = 0; nt < 4; ++nt) acc0[nt] = (f32x4){0.f, 0.f, 0.f, 0.f};
    #pragma unroll
    for (int kc = 0; kc < 4; ++kc) {
        #pragma unroll
        for (int nt = 0; nt < 4; ++nt) {
            bf16x8 b = ((const bf16x8*)(wsu + F0_U16 + (kc * 4 + nt) * 512))[lane];
            acc0[nt] = __builtin_amdgcn_mfma_f32_16x16x32_bf16(a0[kc], b, acc0[nt], 0, 0, 0);
        }
    }
    // epilogue: h0[m][n] = relu(c + b0[n]) as bf16; C layout: m=quad*4+r, n=nt*16+l15
    #pragma unroll
    for (int nt = 0; nt < 4; ++nt) {
        const int n = nt * 16 + l15;
        const float bias = wsf[B0_F + n];
        #pragma unroll
        for (int r = 0; r < 4; ++r) {
            const int m = quad * 4 + r;
            h0u[m * 88 + n] = f2bf(fmaxf(acc0[nt][r] + bias, 0.0f));
        }
    }
    __syncthreads();

    // ================= Layer 1: C1[16,64] = h0[16,64] * B1[64,64] =================
    bf16x8 a1[2];
    #pragma unroll
    for (int kc = 0; kc < 2; ++kc)
        a1[kc] = *(const bf16x8*)(h0u + l15 * 88 + kc * 32 + quad * 8);

    f32x4 acc1[4];
    #pragma unroll
    for (int nt = 0; nt < 4; ++nt) acc1[nt] = (f32x4){0.f, 0.f, 0.f, 0.f};
    #pragma unroll
    for (int kc = 0; kc < 2; ++kc) {
        #pragma unroll
        for (int nt = 0; nt < 4; ++nt) {
            bf16x8 b = ((const bf16x8*)(wsu + F1_U16 + (kc * 4 + nt) * 512))[lane];
            acc1[nt] = __builtin_amdgcn_mfma_f32_16x16x32_bf16(a1[kc], b, acc1[nt], 0, 0, 0);
        }
    }
    #pragma unroll
    for (int nt = 0; nt < 4; ++nt) {
        const int n = nt * 16 + l15;
        const float bias = wsf[B1_F + n];
        #pragma unroll
        for (int r = 0; r < 4; ++r) {
            const int m = quad * 4 + r;
            h1u[m * 88 + n] = f2bf(fmaxf(acc1[nt][r] + bias, 0.0f));
        }
    }
    __syncthreads();

    // ================= Layer 2: O[16,112] = h1[16,64] * B2[64,112] =================
    bf16x8 a2[2];
    #pragma unroll
    for (int kc = 0; kc < 2; ++kc)
        a2[kc] = *(const bf16x8*)(h1u + l15 * 88 + kc * 32 + quad * 8);

    f32x4 acc2[7];
    #pragma unroll
    for (int nt = 0; nt < 7; ++nt) acc2[nt] = (f32x4){0.f, 0.f, 0.f, 0.f};
    #pragma unroll
    for (int kc = 0; kc < 2; ++kc) {
        #pragma unroll
        for (int nt = 0; nt < 7; ++nt) {
            bf16x8 b = ((const bf16x8*)(wsu + F2_U16 + (kc * 7 + nt) * 512))[lane];
            acc2[nt] = __builtin_amdgcn_mfma_f32_16x16x32_bf16(a2[kc], b, acc2[nt], 0, 0, 0);
        }
    }
    __syncthreads();   // h0/h1 dead; O overlays the slab

    // O epilogue: o[m][t] = c + b2[t], t<99, f32, stride 116
    #pragma unroll
    for (int nt = 0; nt < 7; ++nt) {
        const int t = nt * 16 + l15;
        if (t < 99) {
            const float bias = wsf[B2_F + t];
            #pragma unroll
            for (int r = 0; r < 4; ++r) {
                const int m = quad * 4 + r;
                slabF[m * 116 + t] = acc2[nt][r] + bias;
            }
        }
    }
    __syncthreads();

    // ================= Euler scan: lane j scans row j (lanes 0..15) =================
    if (lane < 16) {
        float* orow = slabF + lane * 116;
        float prev = I0_C;
        #pragma unroll
        for (int k = 1; k < TT; ++k) {
            const float o = orow[k - 1];
            orow[k - 1] = prev;                  // I[k-1] overwrites consumed o
            prev = prev + DT_C * (o * prev * (1.0f - prev) - GAMMA_C * prev);
        }
        orow[TT - 1] = prev;
    }
    __syncthreads();

    // ================= Coalesced burst store: 16 rows x 400 B contiguous =================
    float* gout = out + (size_t)row0 * 100;
    #pragma unroll
    for (int q2 = 0; q2 < 7; ++q2) {
        const int i = q2 * 64 + lane;            // float4 index, 400 total
        if (i < 400) {
            const int m = i / 25, c4 = (i % 25) * 4;
            f32x4 v = *(const f32x4*)(slabF + m * 116 + c4);
            *(f32x4*)(gout + 4 * i) = v;
        }
    }
}

extern "C" void kernel_launch(void* const* d_in, const int* in_sizes, int n_in,
                              void* d_out, int out_size, void* d_ws, size_t ws_size,
                              hipStream_t stream) {
    const float* x  = (const float*)d_in[0];
    const float* W0 = (const float*)d_in[1];
    const float* b0 = (const float*)d_in[2];
    const float* W1 = (const float*)d_in[3];
    const float* b1 = (const float*)d_in[4];
    const float* W2 = (const float*)d_in[5];
    const float* b2 = (const float*)d_in[6];
    float* out = (float*)d_out;
    uint16_t* wsu = (uint16_t*)d_ws;

    pack_kernel<<<dim3(80), dim3(256), 0, stream>>>(W0, b0, W1, b1, W2, b2, wsu);
    net_kernel<<<dim3(BB / 64), dim3(256), 0, stream>>>(x, (const void*)wsu, out);
}

// Round 7
// 123.597 us; speedup vs baseline: 2.7472x; 1.0055x over previous
//
#include <hip/hip_runtime.h>
#include <stdint.h>

// Problem constants
#define BB      131072
#define TT      100
#define DT_C    0.01f
#define GAMMA_C 0.05f
#define I0_C    0.12f

typedef short bf16x8 __attribute__((ext_vector_type(8)));
typedef float f32x4  __attribute__((ext_vector_type(4)));

// ws layout: 38 B-fragments (bf16 as u16). Bias folded in as extra K-row
// (k=100 for L0, k=50 for L1/L2, paired with activation 1.0). W2,b2 pre-scaled by dt.
// Fragment = 1024 B; lane L holds B[k=kc*32+(L>>4)*8+j][n=nt*16+(L&15)], j=0..7.
#define F0_U16  0           // L0: 16 frags (kc 0..3, nt 0..3), K=100+bias->128, N=50->64
#define F1_U16  (16*512)    // L1: 8 frags  (kc 0..1, nt 0..3), K=50+bias->64,  N=50->64
#define F2_U16  (24*512)    // L2: 14 frags (kc 0..1, nt 0..6), K=50+bias->64,  N=99->112
#define NFRAG_U16 (38*512)  // 19456 u16 = 38,912 B

__device__ __forceinline__ uint16_t f2bf(float x) {
    uint32_t u = __builtin_bit_cast(uint32_t, x);
    return (uint16_t)((u + 0x7fffu + ((u >> 16) & 1u)) >> 16);   // RTNE
}

// Packed f32x2 -> bf16x2 in a u32 (lo = a, hi = b), pure integer RTNE.
__device__ __forceinline__ uint32_t pk2(float a, float b) {
    return (uint32_t)f2bf(a) | ((uint32_t)f2bf(b) << 16);
}

__global__ void pack_kernel(const float* __restrict__ W0, const float* __restrict__ b0,
                            const float* __restrict__ W1, const float* __restrict__ b1,
                            const float* __restrict__ W2, const float* __restrict__ b2,
                            uint16_t* __restrict__ wsu)
{
    const int gid = blockIdx.x * blockDim.x + threadIdx.x;
    const int gsz = gridDim.x * blockDim.x;
    for (int idx = gid; idx < NFRAG_U16; idx += gsz) {
        int f = idx >> 9;
        int r = idx & 511;
        int L = r >> 3, j = r & 7;
        int k8 = ((L >> 4) << 3) + j;
        int n16 = L & 15;
        float v = 0.0f;
        if (f < 16) {                    // B0[k][n]: W0[n][k] for k<100; b0[n] at k==100
            int kc = f >> 2, nt = f & 3;
            int kk = kc * 32 + k8, nn = nt * 16 + n16;
            if (nn < 50) {
                if (kk < 100) v = W0[nn * 100 + kk];
                else if (kk == 100) v = b0[nn];
            }
        } else if (f < 24) {             // B1[k][n]: W1[n][k] for k<50; b1[n] at k==50
            int g = f - 16; int kc = g >> 2, nt = g & 3;
            int kk = kc * 32 + k8, nn = nt * 16 + n16;
            if (nn < 50) {
                if (kk < 50) v = W1[nn * 50 + kk];
                else if (kk == 50) v = b1[nn];
            }
        } else {                         // B2[k][t]: dt*W2[t][k] for k<50; dt*b2[t] at k==50
            int g = f - 24; int kc = g / 7, nt = g % 7;
            int kk = kc * 32 + k8, nn = nt * 16 + n16;
            if (nn < 99) {
                if (kk < 50) v = DT_C * W2[nn * 50 + kk];
                else if (kk == 50) v = DT_C * b2[nn];
            }
        }
        wsu[idx] = f2bf(v);
    }
}

// Per-wave LDS slab (wave-private -> NO barriers anywhere):
//   h0: u16 [32 m][88 n]   at +0 B       (5632 B)
//   h1: u16 [32 m][88 n]   at +5632 B    (5632 B)
//   O:  f32 [32 m][116 t]  at +0 B       (14848 B), overlays h0/h1 after a2 is read
#define SLAB_F 3712   // 32*116 floats = 14848 B per wave

__global__ __launch_bounds__(256, 2) void net_kernel(
    const float* __restrict__ x,
    const void*  __restrict__ wsv,
    float* __restrict__ out)
{
    __shared__ float lds[4 * SLAB_F];    // 59,392 B -> 2 blocks/CU
    const int tid  = threadIdx.x;
    const int wave = tid >> 6, lane = tid & 63;
    const int quad = lane >> 4, l15 = lane & 15;
    float* slabF = lds + wave * SLAB_F;
    uint16_t* h0u = (uint16_t*)slabF;
    uint16_t* h1u = (uint16_t*)slabF + 32 * 88;
    const uint16_t* wsu = (const uint16_t*)wsv;

    const int row0 = (blockIdx.x * 4 + wave) * 32;   // this wave's 32 batch rows

    // ================= A0 fragments: two 16-row halves, f32 -> bf16 =================
    bf16x8 a0[2][4];
    #pragma unroll
    for (int h = 0; h < 2; ++h) {
        const float* xrow = x + (size_t)(row0 + h * 16 + l15) * 100;
        #pragma unroll
        for (int kc = 0; kc < 3; ++kc) {
            f32x4 p = *(const f32x4*)(xrow + kc * 32 + quad * 8);
            f32x4 q = *(const f32x4*)(xrow + kc * 32 + quad * 8 + 4);
            union { bf16x8 v; uint32_t u[4]; } t;
            t.u[0] = pk2(p[0], p[1]); t.u[1] = pk2(p[2], p[3]);
            t.u[2] = pk2(q[0], q[1]); t.u[3] = pk2(q[2], q[3]);
            a0[h][kc] = t.v;
        }
        union { bf16x8 v; uint32_t u[4]; } t;
        t.u[0] = t.u[1] = t.u[2] = t.u[3] = 0u;
        if (quad == 0) {                       // k 96..99 from x; k=100 = bias activation 1.0
            f32x4 p = *(const f32x4*)(xrow + 96);
            t.u[0] = pk2(p[0], p[1]); t.u[1] = pk2(p[2], p[3]);
            t.u[2] = 0x00003f80u;              // bf16(1.0) in low half (k=100)
        }
        a0[h][3] = t.v;
    }

    // ================= Layer 0: C0[32,64] = x~[32,128] * B0[128,64] =================
    f32x4 acc0[2][4];
    #pragma unroll
    for (int h = 0; h < 2; ++h)
        #pragma unroll
        for (int nt = 0; nt < 4; ++nt) acc0[h][nt] = (f32x4){0.f, 0.f, 0.f, 0.f};
    #pragma unroll
    for (int kc = 0; kc < 4; ++kc) {
        #pragma unroll
        for (int nt = 0; nt < 4; ++nt) {
            bf16x8 b = ((const bf16x8*)(wsu + F0_U16 + (kc * 4 + nt) * 512))[lane];
            acc0[0][nt] = __builtin_amdgcn_mfma_f32_16x16x32_bf16(a0[0][kc], b, acc0[0][nt], 0, 0, 0);
            acc0[1][nt] = __builtin_amdgcn_mfma_f32_16x16x32_bf16(a0[1][kc], b, acc0[1][nt], 0, 0, 0);
        }
    }
    // epilogue: h0 = relu(C0) bf16; n==50 gets activation 1.0 (bias row for L1)
    const bool is50 = (l15 == 2);
    #pragma unroll
    for (int h = 0; h < 2; ++h) {
        #pragma unroll
        for (int nt = 0; nt < 4; ++nt) {
            const int n = nt * 16 + l15;
            #pragma unroll
            for (int r2 = 0; r2 < 4; r2 += 2) {
                float v0 = fmaxf(acc0[h][nt][r2], 0.0f);
                float v1 = fmaxf(acc0[h][nt][r2 + 1], 0.0f);
                if (nt == 3 && is50) { v0 = 1.0f; v1 = 1.0f; }
                uint32_t p = pk2(v0, v1);
                const int m = h * 16 + quad * 4 + r2;
                h0u[m * 88 + n]       = (uint16_t)p;
                h0u[(m + 1) * 88 + n] = (uint16_t)(p >> 16);
            }
        }
    }

    // ================= Layer 1: C1[32,64] = h0[32,64] * B1[64,64] =================
    bf16x8 a1[2][2];
    #pragma unroll
    for (int h = 0; h < 2; ++h)
        #pragma unroll
        for (int kc = 0; kc < 2; ++kc)
            a1[h][kc] = *(const bf16x8*)(h0u + (h * 16 + l15) * 88 + kc * 32 + quad * 8);

    f32x4 acc1[2][4];
    #pragma unroll
    for (int h = 0; h < 2; ++h)
        #pragma unroll
        for (int nt = 0; nt < 4; ++nt) acc1[h][nt] = (f32x4){0.f, 0.f, 0.f, 0.f};
    #pragma unroll
    for (int kc = 0; kc < 2; ++kc) {
        #pragma unroll
        for (int nt = 0; nt < 4; ++nt) {
            bf16x8 b = ((const bf16x8*)(wsu + F1_U16 + (kc * 4 + nt) * 512))[lane];
            acc1[0][nt] = __builtin_amdgcn_mfma_f32_16x16x32_bf16(a1[0][kc], b, acc1[0][nt], 0, 0, 0);
            acc1[1][nt] = __builtin_amdgcn_mfma_f32_16x16x32_bf16(a1[1][kc], b, acc1[1][nt], 0, 0, 0);
        }
    }
    #pragma unroll
    for (int h = 0; h < 2; ++h) {
        #pragma unroll
        for (int nt = 0; nt < 4; ++nt) {
            const int n = nt * 16 + l15;
            #pragma unroll
            for (int r2 = 0; r2 < 4; r2 += 2) {
                float v0 = fmaxf(acc1[h][nt][r2], 0.0f);
                float v1 = fmaxf(acc1[h][nt][r2 + 1], 0.0f);
                if (nt == 3 && is50) { v0 = 1.0f; v1 = 1.0f; }
                uint32_t p = pk2(v0, v1);
                const int m = h * 16 + quad * 4 + r2;
                h1u[m * 88 + n]       = (uint16_t)p;
                h1u[(m + 1) * 88 + n] = (uint16_t)(p >> 16);
            }
        }
    }

    // ================= Layer 2: O[32,112] = h1[32,64] * B2[64,112] (dt, bias folded) =================
    bf16x8 a2[2][2];
    #pragma unroll
    for (int h = 0; h < 2; ++h)
        #pragma unroll
        for (int kc = 0; kc < 2; ++kc)
            a2[h][kc] = *(const bf16x8*)(h1u + (h * 16 + l15) * 88 + kc * 32 + quad * 8);

    f32x4 acc2[2][7];
    #pragma unroll
    for (int h = 0; h < 2; ++h)
        #pragma unroll
        for (int nt = 0; nt < 7; ++nt) acc2[h][nt] = (f32x4){0.f, 0.f, 0.f, 0.f};
    #pragma unroll
    for (int kc = 0; kc < 2; ++kc) {
        #pragma unroll
        for (int nt = 0; nt < 7; ++nt) {
            bf16x8 b = ((const bf16x8*)(wsu + F2_U16 + (kc * 7 + nt) * 512))[lane];
            acc2[0][nt] = __builtin_amdgcn_mfma_f32_16x16x32_bf16(a2[0][kc], b, acc2[0][nt], 0, 0, 0);
            acc2[1][nt] = __builtin_amdgcn_mfma_f32_16x16x32_bf16(a2[1][kc], b, acc2[1][nt], 0, 0, 0);
        }
    }
    // O epilogue: raw o' = dt*(h1.W2 + b2); no branch, cols t>=99 are harmless zeros
    #pragma unroll
    for (int h = 0; h < 2; ++h) {
        #pragma unroll
        for (int nt = 0; nt < 7; ++nt) {
            const int t = nt * 16 + l15;
            #pragma unroll
            for (int r = 0; r < 4; ++r)
                slabF[(h * 16 + quad * 4 + r) * 116 + t] = acc2[h][nt][r];
        }
    }

    // ================= Euler scan: lane m scans row m (lanes 0..31) =================
    // I_new = I * fma(o', 1-I, 1-dt*gamma), o' = dt*o pre-scaled
    if (lane < 32) {
        float* orow = slabF + lane * 116;
        float prev = I0_C;
        #pragma unroll
        for (int k = 1; k < TT; ++k) {
            const float op = orow[k - 1];
            orow[k - 1] = prev;                  // I[k-1] overwrites consumed o'
            prev = prev * fmaf(op, 1.0f - prev, 1.0f - DT_C * GAMMA_C);
        }
        orow[TT - 1] = prev;
    }

    // ================= Coalesced burst store: 32 rows x 400 B contiguous =================
    float* gout = out + (size_t)row0 * 100;
    #pragma unroll
    for (int q = 0; q < 13; ++q) {
        const int i = q * 64 + lane;             // float4 index, 800 total
        if (i < 800) {
            const int m = i / 25, c4 = (i % 25) * 4;
            f32x4 v = *(const f32x4*)(slabF + m * 116 + c4);
            *(f32x4*)(gout + 4 * i) = v;
        }
    }
}

extern "C" void kernel_launch(void* const* d_in, const int* in_sizes, int n_in,
                              void* d_out, int out_size, void* d_ws, size_t ws_size,
                              hipStream_t stream) {
    const float* x  = (const float*)d_in[0];
    const float* W0 = (const float*)d_in[1];
    const float* b0 = (const float*)d_in[2];
    const float* W1 = (const float*)d_in[3];
    const float* b1 = (const float*)d_in[4];
    const float* W2 = (const float*)d_in[5];
    const float* b2 = (const float*)d_in[6];
    float* out = (float*)d_out;
    uint16_t* wsu = (uint16_t*)d_ws;

    pack_kernel<<<dim3(80), dim3(256), 0, stream>>>(W0, b0, W1, b1, W2, b2, wsu);
    net_kernel<<<dim3(BB / 128), dim3(256), 0, stream>>>(x, (const void*)wsu, out);
}